// Round 9
// baseline (174.821 us; speedup 1.0000x reference)
//
#include <hip/hip_runtime.h>
#include <math.h>

namespace {

constexpr int PN = 131072;
constexpr int SN = 64;
constexpr int EH = 512;
constexpr int EW = 1024;
constexpr float SPI = 162.97466172610083f;  // 512/pi
constexpr float PIF = 3.14159265358979f;

// ---------- packed pair-of-points math (lane = point k) ----------
typedef float f2 __attribute__((ext_vector_type(2)));

__device__ __forceinline__ f2 mk2(float a, float b){ f2 r; r.x=a; r.y=b; return r; }
__device__ __forceinline__ f2 bc2(float s){ return mk2(s,s); }

#if __has_builtin(__builtin_elementwise_fma)
__device__ __forceinline__ f2 fma2(f2 a, f2 b, f2 c){ return __builtin_elementwise_fma(a,b,c); }
#else
__device__ __forceinline__ f2 fma2(f2 a, f2 b, f2 c){ return a*b + c; }
#endif
__device__ __forceinline__ f2 max2(f2 a, f2 b){ return __builtin_elementwise_max(a,b); }
__device__ __forceinline__ f2 min2(f2 a, f2 b){ return __builtin_elementwise_min(a,b); }
__device__ __forceinline__ f2 clamp2(f2 x, float lo, float hi){ return min2(max2(x,bc2(lo)),bc2(hi)); }
__device__ __forceinline__ f2 fabs2(f2 a){ return mk2(fabsf(a.x), fabsf(a.y)); }
__device__ __forceinline__ f2 sqrt2(f2 a){ return mk2(__builtin_amdgcn_sqrtf(a.x), __builtin_amdgcn_sqrtf(a.y)); }
__device__ __forceinline__ f2 rsq2 (f2 a){ return mk2(__builtin_amdgcn_rsqf(a.x),  __builtin_amdgcn_rsqf(a.y)); }
__device__ __forceinline__ f2 rcp2 (f2 a){ return mk2(__builtin_amdgcn_rcpf(a.x),  __builtin_amdgcn_rcpf(a.y)); }
__device__ __forceinline__ f2 sin2 (f2 a){ return mk2(__builtin_amdgcn_sinf(a.x),  __builtin_amdgcn_sinf(a.y)); }
__device__ __forceinline__ f2 cos2 (f2 a){ return mk2(__builtin_amdgcn_cosf(a.x),  __builtin_amdgcn_cosf(a.y)); }
__device__ __forceinline__ f2 floor2(f2 a){ return mk2(floorf(a.x), floorf(a.y)); }

struct V3 { f2 x, y, z; };
__device__ __forceinline__ f2 dot3(V3 a, V3 b){ return fma2(a.x,b.x, fma2(a.y,b.y, a.z*b.z)); }
__device__ __forceinline__ V3 cross3(V3 a, V3 b){
    return V3{ fma2(a.y,b.z, -(a.z*b.y)),
               fma2(a.z,b.x, -(a.x*b.z)),
               fma2(a.x,b.y, -(a.y*b.x)) };
}
__device__ __forceinline__ V3 norm3v(V3 a){
    f2 l2 = fma2(a.x,a.x, fma2(a.y,a.y, a.z*a.z));
    f2 inv = rsq2(max2(l2, bc2(1e-24f)));
    return V3{a.x*inv, a.y*inv, a.z*inv};
}
__device__ __forceinline__ f2 smith2(f2 alpha, f2 c){
    f2 a2 = alpha*alpha;
    f2 den = c + sqrt2(fma2(1.0f - a2, c*c, a2));
    return 2.0f*c*rcp2(den);
}

// packed atan2 (deg-11 odd minimax, ~1e-6 rad)
__device__ __forceinline__ f2 atan2_2(f2 y, f2 x){
    f2 ax = fabs2(x), ay = fabs2(y);
    f2 mx = max2(ax,ay), mn = min2(ax,ay);
    f2 a = mn*rcp2(mx);
    a = mk2(mx.x==0.f?0.f:a.x, mx.y==0.f?0.f:a.y);
    f2 s = a*a;
    f2 p = fma2(s, bc2(-0.01172120f), bc2(0.05265332f));
    p = fma2(s,p,bc2(-0.11643287f));
    p = fma2(s,p,bc2( 0.19354346f));
    p = fma2(s,p,bc2(-0.33262347f));
    p = fma2(s,p,bc2( 0.99997726f));
    f2 r = p*a;
    r = mk2(ay.x>ax.x?1.57079632679f-r.x:r.x, ay.y>ax.y?1.57079632679f-r.y:r.y);
    r = mk2(x.x<0.f?PIF-r.x:r.x,               x.y<0.f?PIF-r.y:r.y);
    return mk2(copysignf(r.x,y.x), copysignf(r.y,y.y));
}
// packed acos (sqrt*poly, ~1e-6 rad); input pre-clamped
__device__ __forceinline__ f2 acos_2(f2 x){
    f2 ax = fabs2(x);
    f2 p = fma2(ax, bc2(-0.0012624911f), bc2(0.0066700901f));
    p = fma2(ax,p,bc2(-0.0170881256f));
    p = fma2(ax,p,bc2( 0.0308918810f));
    p = fma2(ax,p,bc2(-0.0501743046f));
    p = fma2(ax,p,bc2( 0.0889789874f));
    p = fma2(ax,p,bc2(-0.2145988016f));
    p = fma2(ax,p,bc2( 1.5707963050f));
    f2 s = sqrt2(max2(1.0f-ax, bc2(0.f)));
    f2 r = s*p;
    return mk2(x.x>=0.f?r.x:PIF-r.x, x.y>=0.f?r.y:PIF-r.y);
}

// packed uv -> per-point pair indices/weights/border flags
__device__ __forceinline__ void env_addr2(V3 d, int i0[2], int i1[2],
                                          f2& wx, f2& wy, bool atl[2], bool atr[2]){
    f2 tt = atan2_2(d.x, -d.z);
    f2 vv = acos_2(clamp2(d.y, -1.f, 1.f));
    f2 x = fma2(tt, bc2(SPI), bc2(511.5f));
    f2 y = fma2(vv, bc2(SPI), bc2(-0.5f));
    f2 x0f = floor2(x), y0f = floor2(y);
    wx = x - x0f; wy = y - y0f;
    #pragma unroll
    for (int k = 0; k < 2; ++k){
        int ix = (int)(k ? x0f.y : x0f.x);
        int iy = (int)(k ? y0f.y : y0f.x);
        int xb = min(max(ix, 0), EW - 2);
        int yA = min(max(iy, 0), EH - 1);
        int yB = min(max(iy + 1, 0), EH - 1);
        atl[k] = ix < 0;
        atr[k] = ix >= EW - 1;
        i0[k] = (yA << 10) + xb;
        i1[k] = (yB << 10) + xb;
    }
}

// ---------- scalar helpers (blend + fallback) ----------
struct F3 { float x, y, z; };
__device__ __forceinline__ float clampf(float x, float lo, float hi){ return fminf(fmaxf(x,lo),hi); }

__device__ __forceinline__ float fast_atan2s(float y, float x){
    float ax=fabsf(x), ay=fabsf(y);
    float mx=fmaxf(ax,ay), mn=fminf(ax,ay);
    float a = mn*__builtin_amdgcn_rcpf(mx);
    if (mx==0.f) a=0.f;
    float s=a*a;
    float p = fmaf(s,-0.01172120f,0.05265332f);
    p=fmaf(s,p,-0.11643287f); p=fmaf(s,p,0.19354346f);
    p=fmaf(s,p,-0.33262347f); p=fmaf(s,p,0.99997726f);
    float r=p*a;
    if (ay>ax) r=1.57079632679f-r;
    if (x<0.f) r=PIF-r;
    return copysignf(r,y);
}
__device__ __forceinline__ float fast_acoss(float x){
    float ax=fabsf(x);
    float p=fmaf(ax,-0.0012624911f,0.0066700901f);
    p=fmaf(ax,p,-0.0170881256f); p=fmaf(ax,p,0.0308918810f);
    p=fmaf(ax,p,-0.0501743046f); p=fmaf(ax,p,0.0889789874f);
    p=fmaf(ax,p,-0.2145988016f); p=fmaf(ax,p,1.5707963050f);
    float s=__builtin_amdgcn_sqrtf(fmaxf(1.f-ax,0.f));
    float r=s*p;
    return (x>=0.f)?r:PIF-r;
}
__device__ __forceinline__ F3 env_sample_f32(const float* __restrict__ emap, float dx, float dy, float dz){
    const int HW = EH*EW;
    float t = fast_atan2s(dx, -dz);
    float vv = fast_acoss(clampf(dy,-1.f,1.f));
    float x = fmaf(t, SPI, 511.5f);
    float y = fmaf(vv, SPI, -0.5f);
    float x0f=floorf(x), y0f=floorf(y);
    float wx=x-x0f, wy=y-y0f;
    int ix=(int)x0f, iy=(int)y0f;
    int xb=min(max(ix,0),EW-2);
    int yA=min(max(iy,0),EH-1);
    int yB=min(max(iy+1,0),EH-1);
    int x0 = (ix>=EW-1)?1:0, x1=(ix<0)?0:1;
    int i0=(yA<<10)+xb, i1=(yB<<10)+xb;
    F3 o; float* po=&o.x;
    #pragma unroll
    for(int c=0;c<3;++c){
        const float* pl=emap+c*HW;
        float v00=pl[i0+x0], v01=pl[i0+x1];
        float v10=pl[i1+x0], v11=pl[i1+x1];
        float r0=fmaf(wx,v01-v00,v00);
        float r1=fmaf(wx,v11-v10,v10);
        po[c]=fmaf(wy,r1-r0,r0);
    }
    return o;
}

// RGB9E5 decode-accumulate
__device__ __forceinline__ void rgb9e5_addmul(unsigned int v, float w, F3& acc){
    float scale = __uint_as_float(((v >> 27) + 103u) << 23);  // 2^(e-24)
    float ws = w * scale;
    acc.x = fmaf((float)(v & 511u), ws, acc.x);
    acc.y = fmaf((float)((v >> 9) & 511u), ws, acc.y);
    acc.z = fmaf((float)((v >> 18) & 511u), ws, acc.z);
}
__device__ __forceinline__ F3 env_blend9(uint2 r0, uint2 r1, float wx, float wy,
                                         bool at_l, bool at_r){
    unsigned int t00 = at_r ? r0.y : r0.x;
    unsigned int t01 = at_l ? r0.x : r0.y;
    unsigned int t10 = at_r ? r1.y : r1.x;
    unsigned int t11 = at_l ? r1.x : r1.y;
    float w00 = (1.0f-wx)*(1.0f-wy);
    float w01 = wx*(1.0f-wy);
    float w10 = (1.0f-wx)*wy;
    float w11 = wx*wy;
    F3 acc{0.f,0.f,0.f};
    rgb9e5_addmul(t00,w00,acc);
    rgb9e5_addmul(t01,w01,acc);
    rgb9e5_addmul(t10,w10,acc);
    rgb9e5_addmul(t11,w11,acc);
    return acc;
}

// wave64 sum via DPP; total lands in lane 63
template<int CTRL, int ROW_MASK, bool BCF>
__device__ __forceinline__ float dpp_add_step(float x){
    int ti = __builtin_amdgcn_update_dpp(0, __float_as_int(x), CTRL, ROW_MASK, 0xf, BCF);
    return x + __int_as_float(ti);
}
__device__ __forceinline__ float wave_sum63(float x){
    x = dpp_add_step<0x111,0xf,true >(x);
    x = dpp_add_step<0x112,0xf,true >(x);
    x = dpp_add_step<0x114,0xf,true >(x);
    x = dpp_add_step<0x118,0xf,true >(x);
    x = dpp_add_step<0x142,0xa,false>(x);
    x = dpp_add_step<0x143,0xc,false>(x);
    return x;
}

__global__ void relayout_kernel(const float* __restrict__ img, unsigned int* __restrict__ tex){
    int i = blockIdx.x*blockDim.x + threadIdx.x;
    const int HW = EH*EW;
    if (i < HW){
        float r = img[i], g = img[HW+i], b = img[2*HW+i];
        float m = fmaxf(fmaxf(r,g),b);
        int es = min(max((int)(__float_as_uint(m)>>23) - 111, 0), 31);
        float sc = __uint_as_float((unsigned int)(151-es)<<23);
        unsigned int R = min(511u,(unsigned int)rintf(r*sc));
        unsigned int G = min(511u,(unsigned int)rintf(g*sc));
        unsigned int B = min(511u,(unsigned int)rintf(b*sc));
        tex[i] = ((unsigned int)es<<27)|(B<<18)|(G<<9)|R;
    }
}

template<bool TEX>
__global__ __launch_bounds__(256) void ibl_kernel(
    const float* __restrict__ emap, const unsigned int* __restrict__ tex,
    const float* __restrict__ view_dir, const float* __restrict__ normal,
    const float* __restrict__ albedo, const float* __restrict__ rough_,
    const float* __restrict__ metal_, const float* __restrict__ u1_,
    const float* __restrict__ u2_, const float* __restrict__ uc_,
    const float* __restrict__ vc_, float* __restrict__ out)
{
    int lane = threadIdx.x & 63;
    int wid  = (blockIdx.x << 2) + (threadIdx.x >> 6);
    int p0   = __builtin_amdgcn_readfirstlane(wid << 1);  // 2 points per wave

    // ---- load & pack (f2 lane = point k) ----
    float u1s[2],u2s[2],ucs[2],vcs[2];
    float vx[2],vy[2],vz[2], nx[2],ny[2],nz[2], ax_[2],ay_[2],az_[2], rg[2], mt[2];
    #pragma unroll
    for (int k=0;k<2;++k){
        int p = p0+k;
        size_t si = (size_t)p*SN + lane;
        u1s[k]=__builtin_nontemporal_load(u1_+si);
        u2s[k]=__builtin_nontemporal_load(u2_+si);
        ucs[k]=__builtin_nontemporal_load(uc_+si);
        vcs[k]=__builtin_nontemporal_load(vc_+si);
        vx[k]=view_dir[3*p]; vy[k]=view_dir[3*p+1]; vz[k]=view_dir[3*p+2];
        nx[k]=normal[3*p];   ny[k]=normal[3*p+1];   nz[k]=normal[3*p+2];
        ax_[k]=albedo[3*p];  ay_[k]=albedo[3*p+1];  az_[k]=albedo[3*p+2];
        rg[k]=rough_[p];     mt[k]=metal_[p];
    }
    f2 U1=mk2(u1s[0],u1s[1]), U2=mk2(u2s[0],u2s[1]);
    f2 UC=mk2(ucs[0],ucs[1]), VC=mk2(vcs[0],vcs[1]);
    V3 v  = {mk2(vx[0],vx[1]), mk2(vy[0],vy[1]), mk2(vz[0],vz[1])};
    V3 n  = {mk2(nx[0],nx[1]), mk2(ny[0],ny[1]), mk2(nz[0],nz[1])};
    V3 alb= {mk2(ax_[0],ax_[1]),mk2(ay_[0],ay_[1]),mk2(az_[0],az_[1])};
    f2 rough = mk2(rg[0],rg[1]);
    f2 alpha = rough*rough;
    f2 metal = mk2(mt[0],mt[1]);

    // ---- TBN (packed) ----
    f2 nx2nz2 = fma2(n.x,n.x, n.z*n.z);
    f2 invt = rsq2(nx2nz2);
    f2 tx = n.z*invt, tz = -(n.x*invt);
    tx = mk2(nx2nz2.x<=0.f?1.f:tx.x, nx2nz2.y<=0.f?1.f:tx.y);
    tz = mk2(nx2nz2.x<=0.f?0.f:tz.x, nx2nz2.y<=0.f?0.f:tz.y);
    V3 t = {tx, bc2(0.f), tz};
    V3 b = cross3(n, t);   // unit to ~1e-7

    // ---- diffuse dir (short chain) -> issue gathers FIRST ----
    f2 sph = sin2(UC), cph = cos2(UC);
    f2 ct = sqrt2(VC);
    f2 st = sqrt2(max2(1.0f-VC, bc2(0.f)));
    f2 lx = cph*st, ly = sph*st;   // local
    V3 ld = { fma2(t.x,lx, fma2(b.x,ly, n.x*ct)),
              fma2(t.y,lx, fma2(b.y,ly, n.y*ct)),
              fma2(t.z,lx, fma2(b.z,ly, n.z*ct)) };
    int di0[2], di1[2]; f2 dwx, dwy; bool d_l[2], d_r[2];
    uint2 dr0[2], dr1[2];
    if (TEX){
        env_addr2(ld, di0, di1, dwx, dwy, d_l, d_r);
        #pragma unroll
        for (int k=0;k<2;++k){
            dr0[k] = *reinterpret_cast<const uint2*>(tex + di0[k]);
            dr1[k] = *reinterpret_cast<const uint2*>(tex + di1[k]);
        }
    }

    // ---- spec chain (packed; hides diffuse-load latency) ----
    V3 vl = { dot3(t,v), dot3(b,v), dot3(n,v) };
    f2 ndv = clamp2(vl.z, 0.f, 1.f);
    f2 s_ndv = smith2(alpha, ndv);
    f2 sv_ratio = mk2(s_ndv.x>=1e-10f?1.f:s_ndv.x*1e10f,
                      s_ndv.y>=1e-10f?1.f:s_ndv.y*1e10f);

    V3 vh = norm3v({vl.x*alpha, vl.y*alpha, vl.z});
    f2 l2d = fma2(vh.x,vh.x, vh.y*vh.y);
    f2 invb = rsq2(l2d);
    f2 b1x = -(vh.y*invb), b1y = vh.x*invb;
    b1x = mk2(l2d.x<=0.f?1.f:b1x.x, l2d.y<=0.f?1.f:b1x.y);
    b1y = mk2(l2d.x<=0.f?0.f:b1y.x, l2d.y<=0.f?0.f:b1y.y);
    V3 b1 = {b1x, b1y, bc2(0.f)};
    V3 b2 = cross3(vh, b1);
    f2 sfac = fma2(vh.z, bc2(0.5f), bc2(0.5f));

    f2 r = sqrt2(U1);
    f2 sth = sin2(U2), cth = cos2(U2);
    f2 t1 = r*cth;
    f2 t2 = r*sth;
    t2 = fma2(1.0f - sfac, sqrt2(max2(1.0f - t1*t1, bc2(0.f))), sfac*t2);
    f2 t3 = sqrt2(clamp2(1.0f - t1*t1 - t2*t2, 0.f, 1.f));
    V3 mh = { fma2(b1.x,t1, fma2(b2.x,t2, vh.x*t3)),
              fma2(b1.y,t1, fma2(b2.y,t2, vh.y*t3)),
              fma2(b1.z,t1, fma2(b2.z,t2, vh.z*t3)) };
    V3 ml = norm3v({mh.x*alpha, mh.y*alpha, mh.z});
    V3 m3 = { fma2(t.x,ml.x, fma2(b.x,ml.y, n.x*ml.z)),
              fma2(t.y,ml.x, fma2(b.y,ml.y, n.y*ml.z)),
              fma2(t.z,ml.x, fma2(b.z,ml.y, n.z*ml.z)) };
    f2 idm = 2.0f*dot3(v, m3);
    V3 light = { fma2(idm, m3.x, -v.x),
                 fma2(idm, m3.y, -v.y),
                 fma2(idm, m3.z, -v.z) };   // unit reflect of unit v

    int si0[2], si1[2]; f2 swx, swy; bool s_l[2], s_r[2];
    uint2 sr0[2], sr1[2];
    if (TEX){
        env_addr2(light, si0, si1, swx, swy, s_l, s_r);
        #pragma unroll
        for (int k=0;k<2;++k){
            sr0[k] = *reinterpret_cast<const uint2*>(tex + si0[k]);
            sr1[k] = *reinterpret_cast<const uint2*>(tex + si1[k]);
        }
    }

    // ---- shading scalars (packed; hide spec-load latency) ----
    f2 cvl = dot3(v, light);
    f2 hdv = sqrt2(clamp2(fma2(cvl, bc2(0.5f), bc2(0.5f)), 0.f, 1.f));
    f2 ndl = clamp2(dot3(n, light), 0.f, 1.f);
    f2 s_ndl = smith2(alpha, ndl);
    f2 gs = sv_ratio * s_ndl;
    f2 om = 1.0f - hdv;
    f2 om2 = om*om;
    f2 om5 = om2*om2*om;
    f2 one_mt = 1.0f - metal;
    V3 f0 = { fma2(metal, alb.x, one_mt*0.04f),
              fma2(metal, alb.y, one_mt*0.04f),
              fma2(metal, alb.z, one_mt*0.04f) };
    V3 kd = { alb.x*one_mt, alb.y*one_mt, alb.z*one_mt };
    // spec coefficient per channel: (f0 + (1-f0)*om5) * gs
    V3 cf = { fma2(1.0f - f0.x, om5, f0.x)*gs,
              fma2(1.0f - f0.y, om5, f0.y)*gs,
              fma2(1.0f - f0.z, om5, f0.z)*gs };

    // ---- blends (scalar per k) + packed combine ----
    F3 radk[2], raddk[2];
    #pragma unroll
    for (int k=0;k<2;++k){
        if (TEX){
            raddk[k] = env_blend9(dr0[k], dr1[k], k?dwx.y:dwx.x, k?dwy.y:dwy.x, d_l[k], d_r[k]);
            radk[k]  = env_blend9(sr0[k], sr1[k], k?swx.y:swx.x, k?swy.y:swy.x, s_l[k], s_r[k]);
        } else {
            raddk[k] = env_sample_f32(emap, k?ld.x.y:ld.x.x, k?ld.y.y:ld.y.x, k?ld.z.y:ld.z.x);
            radk[k]  = env_sample_f32(emap, k?light.x.y:light.x.x, k?light.y.y:light.y.x, k?light.z.y:light.z.x);
        }
    }
    V3 rad  = {mk2(radk[0].x,radk[1].x),  mk2(radk[0].y,radk[1].y),  mk2(radk[0].z,radk[1].z)};
    V3 radd = {mk2(raddk[0].x,raddk[1].x),mk2(raddk[0].y,raddk[1].y),mk2(raddk[0].z,raddk[1].z)};

    V3 acc = { fma2(cf.x, rad.x, radd.x*kd.x),
               fma2(cf.y, rad.y, radd.y*kd.y),
               fma2(cf.z, rad.z, radd.z*kd.z) };

    // ---- DPP reduce + store ----
    #pragma unroll
    for (int k=0;k<2;++k){
        float sx = wave_sum63(k?acc.x.y:acc.x.x);
        float sy = wave_sum63(k?acc.y.y:acc.y.x);
        float sz = wave_sum63(k?acc.z.y:acc.z.x);
        if (lane == 63){
            const float inv_s = 1.0f/(float)SN;
            int p = p0 + k;
            __builtin_nontemporal_store(sx*inv_s, out + 3*p + 0);
            __builtin_nontemporal_store(sy*inv_s, out + 3*p + 1);
            __builtin_nontemporal_store(sz*inv_s, out + 3*p + 2);
        }
    }
}

} // anonymous namespace

extern "C" void kernel_launch(void* const* d_in, const int* in_sizes, int n_in,
                              void* d_out, int out_size, void* d_ws, size_t ws_size,
                              hipStream_t stream) {
    const float* emap     = (const float*)d_in[0];
    const float* view_dir = (const float*)d_in[1];
    const float* normal   = (const float*)d_in[2];
    const float* albedo   = (const float*)d_in[3];
    const float* rough    = (const float*)d_in[4];
    const float* metal    = (const float*)d_in[5];
    const float* u1       = (const float*)d_in[6];
    const float* u2       = (const float*)d_in[7];
    const float* uc       = (const float*)d_in[8];
    const float* vc       = (const float*)d_in[9];
    float* out            = (float*)d_out;

    const int HW = EH*EW;
    const size_t tex_bytes = (size_t)HW*sizeof(unsigned int);
    const int main_blocks = PN/8;   // 4 waves/block x 2 points/wave

    if (ws_size >= tex_bytes) {
        unsigned int* tex = (unsigned int*)d_ws;
        relayout_kernel<<<(HW + 255)/256, 256, 0, stream>>>(emap, tex);
        ibl_kernel<true><<<main_blocks, 256, 0, stream>>>(
            emap, tex, view_dir, normal, albedo, rough, metal, u1, u2, uc, vc, out);
    } else {
        ibl_kernel<false><<<main_blocks, 256, 0, stream>>>(
            emap, nullptr, view_dir, normal, albedo, rough, metal, u1, u2, uc, vc, out);
    }
}

// Round 10
// 150.848 us; speedup vs baseline: 1.1589x; 1.1589x over previous
//
#include <hip/hip_runtime.h>
#include <math.h>

namespace {

constexpr int PN = 131072;
constexpr int SN = 64;
constexpr int EH = 512;
constexpr int EW = 1024;
constexpr float SPI = 162.97466172610083f;  // 512/pi

struct F3 { float x, y, z; };

__device__ __forceinline__ float dot3(F3 a, F3 b) { return a.x*b.x + a.y*b.y + a.z*b.z; }
__device__ __forceinline__ F3 cross3(F3 a, F3 b) {
    return F3{a.y*b.z - a.z*b.y, a.z*b.x - a.x*b.z, a.x*b.y - a.y*b.x};
}
__device__ __forceinline__ float clampf(float x, float lo, float hi) {
    return fminf(fmaxf(x, lo), hi);
}
__device__ __forceinline__ F3 norm3(F3 a) {
    float l2 = a.x*a.x + a.y*a.y + a.z*a.z;
    float inv = __builtin_amdgcn_rsqf(fmaxf(l2, 1e-24f));
    return F3{a.x*inv, a.y*inv, a.z*inv};
}
__device__ __forceinline__ float smithf(float alpha, float c) {
    float a2 = alpha*alpha;
    float den = c + __builtin_amdgcn_sqrtf(a2 + (1.0f - a2)*c*c);
    return 2.0f*c*__builtin_amdgcn_rcpf(den);
}

// atan2 via degree-11 odd minimax (abs err ~1e-6 rad)
__device__ __forceinline__ float fast_atan2(float y, float x) {
    float ax = fabsf(x), ay = fabsf(y);
    float mx = fmaxf(ax, ay), mn = fminf(ax, ay);
    float a = mn * __builtin_amdgcn_rcpf(mx);
    if (mx == 0.0f) a = 0.0f;
    float s = a*a;
    float p = fmaf(s, -0.01172120f, 0.05265332f);
    p = fmaf(s, p, -0.11643287f);
    p = fmaf(s, p,  0.19354346f);
    p = fmaf(s, p, -0.33262347f);
    p = fmaf(s, p,  0.99997726f);
    float r = p * a;
    if (ay > ax)  r = 1.57079632679f - r;
    if (x < 0.0f) r = 3.14159265359f - r;
    return copysignf(r, y);
}

// acos via sqrt*poly (abs err ~1e-6 rad); x pre-clamped to [-1,1]
__device__ __forceinline__ float fast_acos(float x) {
    float ax = fabsf(x);
    float p = fmaf(ax, -0.0012624911f, 0.0066700901f);
    p = fmaf(ax, p, -0.0170881256f);
    p = fmaf(ax, p,  0.0308918810f);
    p = fmaf(ax, p, -0.0501743046f);
    p = fmaf(ax, p,  0.0889789874f);
    p = fmaf(ax, p, -0.2145988016f);
    p = fmaf(ax, p,  1.5707963050f);
    float s = __builtin_amdgcn_sqrtf(fmaxf(1.0f - ax, 0.0f));
    float r = s * p;
    return (x >= 0.0f) ? r : 3.14159265359f - r;
}

// lat-long uv -> two row-pair texel indices + weights + border flags
// iy in [-1, 511] provably -> one-sided clamps
__device__ __forceinline__ void env_addr(F3 d, int& i0, int& i1,
                                         float& wx, float& wy,
                                         bool& at_l, bool& at_r) {
    float t  = fast_atan2(d.x, -d.z);
    float vv = fast_acos(clampf(d.y, -1.0f, 1.0f));
    float x = fmaf(t,  SPI, 511.5f);   // u*W - 0.5
    float y = fmaf(vv, SPI, -0.5f);    // v*H - 0.5
    float x0f = floorf(x), y0f = floorf(y);
    wx = x - x0f; wy = y - y0f;
    int ix = (int)x0f, iy = (int)y0f;
    int xb = min(max(ix, 0), EW - 2);  // pair base: texels xb, xb+1
    int y0 = max(iy, 0);               // iy <= 511 always
    int y1 = min(iy + 1, EH - 1);      // iy+1 >= 0 always
    at_l = ix < 0;          // both taps -> pair lo
    at_r = ix >= EW - 1;    // both taps -> pair hi
    i0 = (y0 << 10) + xb;
    i1 = (y1 << 10) + xb;
}

// RGB9E5: value = mant * 2^(e-24); accumulate w * texel into acc
__device__ __forceinline__ void rgb9e5_addmul(unsigned int v, float w, F3& acc) {
    float scale = __uint_as_float(((v >> 27) + 103u) << 23);  // 2^(e-24)
    float ws = w * scale;
    acc.x = fmaf((float)(v & 511u), ws, acc.x);
    acc.y = fmaf((float)((v >> 9) & 511u), ws, acc.y);
    acc.z = fmaf((float)((v >> 18) & 511u), ws, acc.z);
}

__device__ __forceinline__ F3 env_blend9(uint2 r0, uint2 r1, float wx, float wy,
                                         bool at_l, bool at_r) {
    unsigned int t00 = at_r ? r0.y : r0.x;
    unsigned int t01 = at_l ? r0.x : r0.y;
    unsigned int t10 = at_r ? r1.y : r1.x;
    unsigned int t11 = at_l ? r1.x : r1.y;
    float w00 = (1.0f - wx)*(1.0f - wy);
    float w01 = wx*(1.0f - wy);
    float w10 = (1.0f - wx)*wy;
    float w11 = wx*wy;
    F3 acc{0.0f, 0.0f, 0.0f};
    rgb9e5_addmul(t00, w00, acc);
    rgb9e5_addmul(t01, w01, acc);
    rgb9e5_addmul(t10, w10, acc);
    rgb9e5_addmul(t11, w11, acc);
    return acc;
}

// ---- wave64 sum via DPP; total lands in lane 63 ----
template<int CTRL, int ROW_MASK, bool BC>
__device__ __forceinline__ float dpp_add_step(float x) {
    int ti = __builtin_amdgcn_update_dpp(0, __float_as_int(x), CTRL, ROW_MASK, 0xf, BC);
    return x + __int_as_float(ti);
}
__device__ __forceinline__ float wave_sum63(float x) {
    x = dpp_add_step<0x111, 0xf, true >(x);  // row_shr:1 (0-fill)
    x = dpp_add_step<0x112, 0xf, true >(x);  // row_shr:2
    x = dpp_add_step<0x114, 0xf, true >(x);  // row_shr:4
    x = dpp_add_step<0x118, 0xf, true >(x);  // row_shr:8
    x = dpp_add_step<0x142, 0xa, false>(x);  // row_bcast15 into rows 1,3
    x = dpp_add_step<0x143, 0xc, false>(x);  // row_bcast31 into rows 2,3 -> lane63
    return x;
}

__global__ void relayout_kernel(const float* __restrict__ img, unsigned int* __restrict__ tex) {
    int i = blockIdx.x*blockDim.x + threadIdx.x;
    const int HW = EH*EW;
    if (i < HW) {
        float r = img[i], g = img[HW + i], b = img[2*HW + i];
        float m = fmaxf(fmaxf(r, g), b);
        int es = min(max((int)(__float_as_uint(m) >> 23) - 111, 0), 31);
        float sc = __uint_as_float((unsigned int)(151 - es) << 23);   // 2^(24-es)
        unsigned int R = min(511u, (unsigned int)rintf(r*sc));
        unsigned int G = min(511u, (unsigned int)rintf(g*sc));
        unsigned int B = min(511u, (unsigned int)rintf(b*sc));
        tex[i] = ((unsigned int)es << 27) | (B << 18) | (G << 9) | R;
    }
}

template<bool TEX>
__global__ __launch_bounds__(256) void ibl_kernel(
    const float* __restrict__ emap, const unsigned int* __restrict__ tex,
    const float* __restrict__ view_dir, const float* __restrict__ normal,
    const float* __restrict__ albedo, const float* __restrict__ rough_,
    const float* __restrict__ metal_, const float* __restrict__ u1_,
    const float* __restrict__ u2_, const float* __restrict__ uc_,
    const float* __restrict__ vc_, float* __restrict__ out)
{
    int lane = threadIdx.x & 63;
    int wid  = (blockIdx.x << 2) + (threadIdx.x >> 6);   // wave id
    int p0   = __builtin_amdgcn_readfirstlane(wid << 1); // 2 points per wave, uniform

    // ---- streamed per-sample inputs (non-temporal; keep texture L2-resident) ----
    float U1[2], U2[2], UC[2], VC[2];
    F3 v[2], n[2], alb[2];
    float alpha[2], metal[2];
    #pragma unroll
    for (int k = 0; k < 2; ++k) {
        int p = p0 + k;
        size_t si = (size_t)p*SN + lane;
        U1[k] = __builtin_nontemporal_load(u1_ + si);
        U2[k] = __builtin_nontemporal_load(u2_ + si);
        UC[k] = __builtin_nontemporal_load(uc_ + si);
        VC[k] = __builtin_nontemporal_load(vc_ + si);
        v[k]   = F3{view_dir[3*p], view_dir[3*p+1], view_dir[3*p+2]};
        n[k]   = F3{normal[3*p],   normal[3*p+1],   normal[3*p+2]};
        alb[k] = F3{albedo[3*p],   albedo[3*p+1],   albedo[3*p+2]};
        float rg = rough_[p];
        alpha[k] = rg*rg;
        metal[k] = metal_[p];
    }

    // ---- per-point frames (direct rsq on squared norm; degen select) ----
    F3 t[2], b[2];
    #pragma unroll
    for (int k = 0; k < 2; ++k) {
        float nx2nz2 = n[k].x*n[k].x + n[k].z*n[k].z;
        float invt = __builtin_amdgcn_rsqf(nx2nz2);
        if (nx2nz2 <= 0.0f) t[k] = F3{1.0f, 0.0f, 0.0f};
        else                t[k] = F3{n[k].z*invt, 0.0f, -n[k].x*invt};
        b[k] = cross3(n[k], t[k]);   // unit to ~1e-7
    }

    // ---- diffuse dirs: short chain, issue gathers FIRST ----
    uint2 dr0[2], dr1[2];
    float dwx[2], dwy[2];
    bool d_l[2], d_r[2];
    F3 ld[2];
    #pragma unroll
    for (int k = 0; k < 2; ++k) {
        float sph = __builtin_amdgcn_sinf(UC[k]);
        float cph = __builtin_amdgcn_cosf(UC[k]);
        float ct = __builtin_amdgcn_sqrtf(VC[k]);
        float st = __builtin_amdgcn_sqrtf(fmaxf(1.0f - VC[k], 0.0f));
        F3 ldl = F3{cph*st, sph*st, ct};
        ld[k] = F3{t[k].x*ldl.x + b[k].x*ldl.y + n[k].x*ldl.z,
                   t[k].y*ldl.x + b[k].y*ldl.y + n[k].y*ldl.z,
                   t[k].z*ldl.x + b[k].z*ldl.y + n[k].z*ldl.z};
        if (TEX) {
            int i0, i1;
            env_addr(ld[k], i0, i1, dwx[k], dwy[k], d_l[k], d_r[k]);
            dr0[k] = *reinterpret_cast<const uint2*>(tex + i0);
            dr1[k] = *reinterpret_cast<const uint2*>(tex + i1);
        }
    }

    // ---- spec chains (VALU hides diffuse-load latency) ----
    uint2 sr0[2], sr1[2];
    float swx[2], swy[2];
    bool s_l[2], s_r[2];
    F3 light[2];
    float sv_ratio[2];
    #pragma unroll
    for (int k = 0; k < 2; ++k) {
        F3 vl = F3{dot3(t[k], v[k]), dot3(b[k], v[k]), dot3(n[k], v[k])};
        float ndv = clampf(vl.z, 0.0f, 1.0f);
        float s_ndv = smithf(alpha[k], ndv);
        // smith in [0,1] -> ratio s_ndv/clip(s_ndv,1e-10,1) is 1 except degenerate
        sv_ratio[k] = (s_ndv >= 1e-10f) ? 1.0f : s_ndv * 1e10f;

        F3 vh = norm3(F3{vl.x*alpha[k], vl.y*alpha[k], vl.z});
        F3 b1;
        float l2d = vh.x*vh.x + vh.y*vh.y;
        float invb = __builtin_amdgcn_rsqf(l2d);
        if (l2d <= 0.0f) b1 = F3{1.0f, 0.0f, 0.0f};
        else             b1 = F3{-vh.y*invb, vh.x*invb, 0.0f};
        F3 b2 = cross3(vh, b1);
        float sfac = 0.5f*(1.0f + vh.z);

        float r = __builtin_amdgcn_sqrtf(U1[k]);
        float sth = __builtin_amdgcn_sinf(U2[k]);
        float cth = __builtin_amdgcn_cosf(U2[k]);
        float t1 = r*cth;
        float t2 = r*sth;
        t2 = (1.0f - sfac)*__builtin_amdgcn_sqrtf(fmaxf(1.0f - t1*t1, 0.0f)) + sfac*t2;
        float t3 = __builtin_amdgcn_sqrtf(clampf(1.0f - t1*t1 - t2*t2, 0.0f, 1.0f));
        F3 mh = F3{t1*b1.x + t2*b2.x + t3*vh.x,
                   t1*b1.y + t2*b2.y + t3*vh.y,
                   t1*b1.z + t2*b2.z + t3*vh.z};
        F3 ml = norm3(F3{mh.x*alpha[k], mh.y*alpha[k], mh.z});
        F3 m = F3{t[k].x*ml.x + b[k].x*ml.y + n[k].x*ml.z,
                  t[k].y*ml.x + b[k].y*ml.y + n[k].y*ml.z,
                  t[k].z*ml.x + b[k].z*ml.y + n[k].z*ml.z};
        float idm = dot3(v[k], m);
        light[k] = F3{fmaf(2.0f*idm, m.x, -v[k].x),
                      fmaf(2.0f*idm, m.y, -v[k].y),
                      fmaf(2.0f*idm, m.z, -v[k].z)};   // unit reflect of unit v
        if (TEX) {
            int i0, i1;
            env_addr(light[k], i0, i1, swx[k], swy[k], s_l[k], s_r[k]);
            sr0[k] = *reinterpret_cast<const uint2*>(tex + i0);
            sr1[k] = *reinterpret_cast<const uint2*>(tex + i1);
        }
    }

    // ---- shading scalars (hide spec-load latency) ----
    float gs[2], om5[2];
    #pragma unroll
    for (int k = 0; k < 2; ++k) {
        // hdv = dot(normalize(v+l), v) == sqrt((1 + v.l)/2) for unit v,l
        float c = dot3(v[k], light[k]);
        float hdv = __builtin_amdgcn_sqrtf(clampf(fmaf(0.5f, c, 0.5f), 0.0f, 1.0f));
        float ndl = clampf(dot3(n[k], light[k]), 0.0f, 1.0f);
        float s_ndl = smithf(alpha[k], ndl);
        gs[k] = sv_ratio[k] * s_ndl;
        float om = 1.0f - hdv;
        float om2 = om*om;
        om5[k] = om2*om2*om;
    }

    // ---- blends + reduce + output (f0/kd folded here) ----
    #pragma unroll
    for (int k = 0; k < 2; ++k) {
        F3 rad, radd;
        if (TEX) {
            radd = env_blend9(dr0[k], dr1[k], dwx[k], dwy[k], d_l[k], d_r[k]);
            rad  = env_blend9(sr0[k], sr1[k], swx[k], swy[k], s_l[k], s_r[k]);
        } else {
            const int HW = EH*EW;
            #pragma unroll
            for (int pass = 0; pass < 2; ++pass) {
                F3 d = pass ? light[k] : ld[k];
                int i0, i1; float wx, wy; bool atl, atr;
                env_addr(d, i0, i1, wx, wy, atl, atr);
                int x0 = atr ? 1 : 0, x1 = atl ? 0 : 1;
                F3 o;
                float* po = &o.x;
                #pragma unroll
                for (int c = 0; c < 3; ++c) {
                    const float* pl = emap + c*HW;
                    float v00 = pl[i0 + x0], v01 = pl[i0 + x1];
                    float v10 = pl[i1 + x0], v11 = pl[i1 + x1];
                    float rr0 = fmaf(wx, v01 - v00, v00);
                    float rr1 = fmaf(wx, v11 - v10, v10);
                    po[c] = fmaf(wy, rr1 - rr0, rr0);
                }
                if (pass) rad = o; else radd = o;
            }
        }
        float mt = metal[k];
        float omt = 1.0f - mt;
        F3 f0 = F3{fmaf(mt, alb[k].x, omt*0.04f),
                   fmaf(mt, alb[k].y, omt*0.04f),
                   fmaf(mt, alb[k].z, omt*0.04f)};
        F3 kd = F3{alb[k].x*omt, alb[k].y*omt, alb[k].z*omt};
        float g = gs[k], o5 = om5[k];
        F3 acc;
        acc.x = fmaf(fmaf(1.0f - f0.x, o5, f0.x)*g, rad.x, radd.x*kd.x);
        acc.y = fmaf(fmaf(1.0f - f0.y, o5, f0.y)*g, rad.y, radd.y*kd.y);
        acc.z = fmaf(fmaf(1.0f - f0.z, o5, f0.z)*g, rad.z, radd.z*kd.z);

        float sx = wave_sum63(acc.x);
        float sy = wave_sum63(acc.y);
        float sz = wave_sum63(acc.z);

        if (lane == 63) {
            const float inv_s = 1.0f/(float)SN;
            int p = p0 + k;
            __builtin_nontemporal_store(sx*inv_s, out + 3*p + 0);
            __builtin_nontemporal_store(sy*inv_s, out + 3*p + 1);
            __builtin_nontemporal_store(sz*inv_s, out + 3*p + 2);
        }
    }
}

} // anonymous namespace

extern "C" void kernel_launch(void* const* d_in, const int* in_sizes, int n_in,
                              void* d_out, int out_size, void* d_ws, size_t ws_size,
                              hipStream_t stream) {
    const float* emap     = (const float*)d_in[0];
    const float* view_dir = (const float*)d_in[1];
    const float* normal   = (const float*)d_in[2];
    const float* albedo   = (const float*)d_in[3];
    const float* rough    = (const float*)d_in[4];
    const float* metal    = (const float*)d_in[5];
    const float* u1       = (const float*)d_in[6];
    const float* u2       = (const float*)d_in[7];
    const float* uc       = (const float*)d_in[8];
    const float* vc       = (const float*)d_in[9];
    float* out            = (float*)d_out;

    const int HW = EH*EW;
    const size_t tex_bytes = (size_t)HW*sizeof(unsigned int);
    const int main_blocks = PN/8;   // 4 waves/block x 2 points/wave

    if (ws_size >= tex_bytes) {
        unsigned int* tex = (unsigned int*)d_ws;
        relayout_kernel<<<(HW + 255)/256, 256, 0, stream>>>(emap, tex);
        ibl_kernel<true><<<main_blocks, 256, 0, stream>>>(
            emap, tex, view_dir, normal, albedo, rough, metal, u1, u2, uc, vc, out);
    } else {
        ibl_kernel<false><<<main_blocks, 256, 0, stream>>>(
            emap, nullptr, view_dir, normal, albedo, rough, metal, u1, u2, uc, vc, out);
    }
}